// Round 5
// baseline (7370.654 us; speedup 1.0000x reference)
//
#include <hip/hip_runtime.h>
#include <hip/hip_bf16.h>
#include <cstdint>

using bf16 = __hip_bfloat16;
typedef unsigned short ushort_t;
typedef unsigned int uint_t;
typedef __bf16 bf16x8 __attribute__((ext_vector_type(8)));
typedef float f32x4 __attribute__((ext_vector_type(4)));

#define MFMA16(a, b, c) __builtin_amdgcn_mfma_f32_16x16x32_bf16(a, b, c, 0, 0, 0)

// f32 -> bf16 bits, round-to-nearest-even
__device__ __forceinline__ ushort_t f2bu(float x) {
  uint_t b = __builtin_bit_cast(uint_t, x);
  b += 0x7FFFu + ((b >> 16) & 1u);
  return (ushort_t)(b >> 16);
}
__device__ __forceinline__ float bu2f(ushort_t u) {
  return __builtin_bit_cast(float, ((uint_t)u) << 16);
}
__device__ __forceinline__ int is_nan_bu(ushort_t u) { return (u & 0x7FFF) > 0x7F80; }

__device__ __forceinline__ float sigm(float x) { return 1.f / (1.f + __expf(-x)); }
__device__ __forceinline__ float tanh_fast(float x) {
  float e = __expf(2.f * x);
  return 1.f - 2.f / (e + 1.f);   // safe at +-inf
}

// ---------------------------------------------------------------------------
// dtype probe: f32 data read as ushorts shows ~0.4% bf16-NaN patterns in the
// mantissa halves; 0.02-scale bf16 data shows none. dflag[3]=1 -> inputs f32.
// ---------------------------------------------------------------------------
__global__ void probe_dtype(const ushort_t* __restrict__ w, int n, int* __restrict__ dflag) {
  __shared__ int cnt;
  if (threadIdx.x == 0) cnt = 0;
  __syncthreads();
  int local = 0;
  for (int i = threadIdx.x; i < n; i += blockDim.x)
    if (is_nan_bu(w[i])) local++;
  if (local) atomicAdd(&cnt, local);
  __syncthreads();
  if (threadIdx.x == 0) dflag[3] = (cnt > 4) ? 1 : 0;
}

// ---------------------------------------------------------------------------
// weight convert (or copy): 4 elements per thread. n4 = element_count/4,
// ALWAYS derived from in_sizes on the host (round-4 abort: hand-computed n4
// for enc_W_ih was 2x -> 8MB OOB read -> HSA fault).
// ---------------------------------------------------------------------------
__global__ void conv_w(const void* __restrict__ in, ushort_t* __restrict__ out,
                       int n4, const int* __restrict__ dflag) {
  int i = blockIdx.x * blockDim.x + threadIdx.x;
  if (i >= n4) return;
  uint2 o;
  if (dflag[3]) {
    float4 v = ((const float4*)in)[i];
    o.x = f2bu(v.x) | ((uint_t)f2bu(v.y) << 16);
    o.y = f2bu(v.z) | ((uint_t)f2bu(v.w) << 16);
  } else {
    o = ((const uint2*)in)[i];
  }
  ((uint2*)out)[i] = o;
}

// ---------------------------------------------------------------------------
// Embedding gather -> bf16 x-buffers. enc row r = flat (B*T) row (reshape
// quirk); dec row t*32+b = label_emb[t==0 ? 1 : label_seq[b][t-1]].
// ---------------------------------------------------------------------------
__global__ void embed_kernel(const int* __restrict__ sentence, const int* __restrict__ label_seq,
                             const void* __restrict__ word_emb, const void* __restrict__ label_emb,
                             ushort_t* __restrict__ enc_x, ushort_t* __restrict__ dec_x,
                             const int* __restrict__ dflag) {
  const int mode = dflag[3];
  int c = blockIdx.x * blockDim.x + threadIdx.x;
  const int encC = 4096 * 128;          // 4-elt chunks: 512/4 per row
  const int decC = 4096 * 64;           // 256/4 per row
  if (c < encC) {
    int r = c >> 7, off = c & 127;
    int tok = sentence[r];
    uint2 o;
    if (mode) {
      float4 v = ((const float4*)word_emb)[(size_t)tok * 128 + off];
      o.x = f2bu(v.x) | ((uint_t)f2bu(v.y) << 16);
      o.y = f2bu(v.z) | ((uint_t)f2bu(v.w) << 16);
    } else {
      o = ((const uint2*)word_emb)[(size_t)tok * 128 + off];
    }
    ((uint2*)enc_x)[(size_t)r * 128 + off] = o;
  } else if (c < encC + decC) {
    int cc = c - encC;
    int r = cc >> 6, off = cc & 63;
    int t = r >> 5, b = r & 31;
    int tok = (t == 0) ? 1 : label_seq[b * 128 + (t - 1)];
    uint2 o;
    if (mode) {
      float4 v = ((const float4*)label_emb)[(size_t)tok * 64 + off];
      o.x = f2bu(v.x) | ((uint_t)f2bu(v.y) << 16);
      o.y = f2bu(v.z) | ((uint_t)f2bu(v.w) << 16);
    } else {
      o = ((const uint2*)label_emb)[(size_t)tok * 64 + off];
    }
    ((uint2*)dec_x)[(size_t)r * 64 + off] = o;
  }
}

// ---------------------------------------------------------------------------
// C(M,N) = A(M,K) @ B(N,K)^T + bias1 + bias2. A,B bf16 bits, fp32 accum.
// biases read per mode (f32 or bf16). Store: final_out&&mode -> f32, else bf16.
// ---------------------------------------------------------------------------
__global__ __launch_bounds__(256) void gemm_bt_bias(
    const ushort_t* __restrict__ A, const ushort_t* __restrict__ B, void* __restrict__ C,
    const void* __restrict__ bias1, const void* __restrict__ bias2,
    int M, int N, int K, const int* __restrict__ dflag, int final_out) {
  __shared__ __align__(16) ushort_t sA[128 * 32];
  __shared__ __align__(16) ushort_t sB[128 * 32];
  const int tid = threadIdx.x;
  const int wave = tid >> 6, lane = tid & 63;
  const int quad = lane >> 4, col = lane & 15;
  const int bm = blockIdx.y * 128, bn = blockIdx.x * 128;
  const int wm = (wave >> 1) * 64, wn = (wave & 1) * 64;

  f32x4 acc[4][4] = {};

  const int c0i = tid, c1i = 256 + tid;
  const int r0 = c0i >> 2, kb0 = c0i & 3;
  const int r1 = c1i >> 2, kb1 = c1i & 3;
  const int j0 = (bn + r0 <= N - 1) ? (bn + r0) : (N - 1);  // clamp N tail
  const int j1 = (bn + r1 <= N - 1) ? (bn + r1) : (N - 1);

  for (int k0 = 0; k0 < K; k0 += 32) {
    uint4 va0 = *(const uint4*)(A + (size_t)(bm + r0) * K + (k0 + kb0 * 8));
    uint4 va1 = *(const uint4*)(A + (size_t)(bm + r1) * K + (k0 + kb1 * 8));
    uint4 vb0 = *(const uint4*)(B + (size_t)j0 * K + (k0 + kb0 * 8));
    uint4 vb1 = *(const uint4*)(B + (size_t)j1 * K + (k0 + kb1 * 8));
    __syncthreads();
    *(uint4*)((char*)sA + c0i * 16) = va0;
    *(uint4*)((char*)sA + c1i * 16) = va1;
    *(uint4*)((char*)sB + c0i * 16) = vb0;
    *(uint4*)((char*)sB + c1i * 16) = vb1;
    __syncthreads();

    bf16x8 af[4], bff[4];
#pragma unroll
    for (int mt = 0; mt < 4; ++mt)
      af[mt] = *(const bf16x8*)&sA[(wm + mt * 16 + col) * 32 + quad * 8];
#pragma unroll
    for (int nt = 0; nt < 4; ++nt)
      bff[nt] = *(const bf16x8*)&sB[(wn + nt * 16 + col) * 32 + quad * 8];
#pragma unroll
    for (int mt = 0; mt < 4; ++mt)
#pragma unroll
      for (int nt = 0; nt < 4; ++nt)
        acc[mt][nt] = MFMA16(af[mt], bff[nt], acc[mt][nt]);
  }

  const int mode = dflag[3];
  const int st_f32 = final_out && mode;
#pragma unroll
  for (int nt = 0; nt < 4; ++nt) {
    int c0 = bn + wn + nt * 16 + col;
    if (c0 >= N) continue;
    float bv = 0.f;
    if (bias1) bv += mode ? ((const float*)bias1)[c0] : bu2f(((const ushort_t*)bias1)[c0]);
    if (bias2) bv += mode ? ((const float*)bias2)[c0] : bu2f(((const ushort_t*)bias2)[c0]);
#pragma unroll
    for (int mt = 0; mt < 4; ++mt) {
      int r0e = bm + wm + mt * 16 + quad * 4;
#pragma unroll
      for (int r = 0; r < 4; ++r) {
        float v = acc[mt][nt][r] + bv;
        size_t idx = (size_t)(r0e + r) * N + c0;
        if (st_f32) ((float*)C)[idx] = v;
        else        ((ushort_t*)C)[idx] = f2bu(v);
      }
    }
  }
}

// ---------------------------------------------------------------------------
// Persistent LSTM recurrence (static LDS, 256 WGs x 256 thr, cooperative).
// ---------------------------------------------------------------------------
#define REC_SLAB  33024           // 16 * 1032 * 2 bytes
#define REC_SMEM  41728           // + 4 waves * 32*17 f32 partials

__device__ __forceinline__ void load_slab(const ushort_t* __restrict__ W, char* slab,
                                          int u0, int tid) {
  for (int i = 0; i < 8; ++i) {
    int c = i * 256 + tid;               // 0..2047 16B chunks
    int s = c >> 7, off = c & 127;
    int j = (s >> 2) * 1024 + u0 + (s & 3);
    *(uint4*)(slab + s * 2064 + off * 16) =
        *(const uint4*)(W + (size_t)j * 1024 + off * 8);
  }
}

__global__ __launch_bounds__(256, 1) void recurrence_kernel(
    const ushort_t* __restrict__ enc_pre, const ushort_t* __restrict__ dec_pre,
    const ushort_t* __restrict__ encW, const ushort_t* __restrict__ decW,
    ushort_t* __restrict__ hbuf, ushort_t* __restrict__ dec_hs, int* __restrict__ flags) {
  __shared__ __align__(16) char smem[REC_SMEM];
  const int tid = threadIdx.x;
  const int wg = blockIdx.x;             // 0..255
  const int wave = tid >> 6, lane = tid & 63;
  const int quad = lane >> 4, col = lane & 15;
  const int u0 = wg * 4;

  load_slab(encW, smem, u0, tid);
  float* part = (float*)(smem + REC_SLAB);
  const int cb = tid >> 2;               // tid<128: batch 0..31
  const int cu = tid & 3;                // unit 0..3
  float c_state = 0.f;
  __syncthreads();

  for (int t = 0; t < 256; ++t) {
    const bool dec = (t >= 128);
    if (t == 128) {
      load_slab(decW, smem, u0, tid);
      __syncthreads();
    }
    const int tt = dec ? (t - 128) : t;
    const ushort_t* pre = dec ? dec_pre : enc_pre;

    float g0 = 0.f, g1 = 0.f, g2 = 0.f, g3 = 0.f;
    if (tid < 128) {
      const ushort_t* prow = pre + ((size_t)(tt * 32 + cb)) * 4096 + u0 + cu;
      g0 = bu2f(prow[0]);
      g1 = bu2f(prow[1024]);
      g2 = bu2f(prow[2048]);
      g3 = bu2f(prow[3072]);
    }

    const ushort_t* hr = hbuf + (size_t)(t & 1) * (32 * 1024);
    const int kbase = wave * 256 + quad * 8;
    const ushort_t* a_base0 = hr + (size_t)col * 1024 + kbase;
    const ushort_t* a_base1 = hr + (size_t)(16 + col) * 1024 + kbase;
    const char* b_base = smem + col * 2064 + kbase * 2;
    f32x4 acc0 = {}, acc1 = {};
#pragma unroll
    for (int kt = 0; kt < 8; ++kt) {
      bf16x8 a0 = *(const bf16x8*)(a_base0 + kt * 32);
      bf16x8 a1 = *(const bf16x8*)(a_base1 + kt * 32);
      bf16x8 b0 = *(const bf16x8*)(b_base + kt * 64);
      acc0 = MFMA16(a0, b0, acc0);
      acc1 = MFMA16(a1, b0, acc1);
    }
    float* pw = part + wave * (32 * 17);
#pragma unroll
    for (int r = 0; r < 4; ++r) {
      pw[(quad * 4 + r) * 17 + col]      = acc0[r];
      pw[(16 + quad * 4 + r) * 17 + col] = acc1[r];
    }
    __syncthreads();

    if (tid < 128) {
#pragma unroll
      for (int w = 0; w < 4; ++w) {
        const float* pr = part + w * (32 * 17) + cb * 17;
        g0 += pr[cu];
        g1 += pr[4 + cu];
        g2 += pr[8 + cu];
        g3 += pr[12 + cu];
      }
      float ig = sigm(g0), fg = sigm(g1), gg = tanh_fast(g2), og = sigm(g3);
      c_state = fg * c_state + ig * gg;
      float hv = og * tanh_fast(c_state);
      ushort_t hb = f2bu(hv);
      ushort_t* hw = hbuf + (size_t)((t + 1) & 1) * (32 * 1024);
      hw[cb * 1024 + u0 + cu] = hb;
      if (dec) dec_hs[((size_t)tt * 32 + cb) * 1024 + u0 + cu] = hb;
    }

    __syncthreads();
    if (tid == 0)
      __hip_atomic_store(&flags[wg], t + 1, __ATOMIC_RELEASE, __HIP_MEMORY_SCOPE_AGENT);
    if (wave == 0) {
      const int target = t + 1;
      for (;;) {
        int f0 = __hip_atomic_load(&flags[lane],       __ATOMIC_RELAXED, __HIP_MEMORY_SCOPE_AGENT);
        int f1 = __hip_atomic_load(&flags[64 + lane],  __ATOMIC_RELAXED, __HIP_MEMORY_SCOPE_AGENT);
        int f2 = __hip_atomic_load(&flags[128 + lane], __ATOMIC_RELAXED, __HIP_MEMORY_SCOPE_AGENT);
        int f3 = __hip_atomic_load(&flags[192 + lane], __ATOMIC_RELAXED, __HIP_MEMORY_SCOPE_AGENT);
        if (__all((f0 >= target) & (f1 >= target) & (f2 >= target) & (f3 >= target))) break;
      }
    }
    __syncthreads();
    __threadfence();
  }
}

// ---------------------------------------------------------------------------
// diagnostics
// ---------------------------------------------------------------------------
__global__ void sentinel_kernel(ushort_t* dec_hs) {
  if (threadIdx.x == 0 && blockIdx.x == 0) dec_hs[0] = 0x46EA;  // ~30000
}

__global__ void scan_b16(const ushort_t* __restrict__ p, size_t n,
                         int* __restrict__ dflag, int slot) {
  size_t i = (size_t)blockIdx.x * blockDim.x + threadIdx.x;
  const size_t stride = (size_t)gridDim.x * blockDim.x;
  int found = 0;
  for (; i < n; i += stride)
    if (is_nan_bu(p[i])) found = 1;
  if (found) dflag[slot] = 1;
}

__global__ void scrub_out(void* __restrict__ out, size_t n, int* __restrict__ dflag) {
  const int mode = dflag[3];
  size_t i = (size_t)blockIdx.x * blockDim.x + threadIdx.x;
  const size_t stride = (size_t)gridDim.x * blockDim.x;
  int found = 0;
  if (mode) {
    float* o = (float*)out;
    for (; i < n; i += stride) {
      uint_t b = __builtin_bit_cast(uint_t, o[i]);
      if ((b & 0x7FFFFFFFu) > 0x7F800000u) { o[i] = 0.f; found = 1; }
    }
  } else {
    ushort_t* o = (ushort_t*)out;
    for (; i < n; i += stride)
      if (is_nan_bu(o[i])) { o[i] = 0; found = 1; }
  }
  if (found) dflag[2] = 1;
}

__global__ void finalize_kernel(void* __restrict__ out, const ushort_t* __restrict__ dec_hs,
                                const int* __restrict__ dflag, int wscode) {
  if (threadIdx.x != 0 || blockIdx.x != 0) return;
  float code = 0.f;
  if (wscode) code = 250.f;                                   // workspace too small
  else if (dflag[0]) code = 1000.f;                           // NaN in pre-gates
  else if (fabsf(bu2f(dec_hs[0])) > 100.f) code = 3000.f;     // recurrence never ran
  else if (dflag[1]) code = 2000.f;                           // NaN in dec_hs
  else if (dflag[2]) code = 4000.f;                           // NaN in out (scrubbed)
  if (code != 0.f) {
    if (dflag[3]) ((float*)out)[0] = code;
    else          ((ushort_t*)out)[0] = f2bu(code);
  }
}

// ---------------------------------------------------------------------------
extern "C" void kernel_launch(void* const* d_in, const int* in_sizes, int n_in,
                              void* d_out, int out_size, void* d_ws, size_t ws_size,
                              hipStream_t stream) {
  const int* sentence   = (const int*)d_in[0];
  const int* label_seq  = (const int*)d_in[1];

  char* ws = (char*)d_ws;
  // ws layout (bytes)
  const size_t OFF_HBUF = 0;                      // 131072 (2 x 32x1024 bf16)
  const size_t OFF_FLAG = 131072;                 // 1024  (256 ints)
  const size_t OFF_DIAG = 132096;                 // 16 (4 ints); pad to 132608
  const size_t OFF_ENCX = 132608;                 // 4,194,304
  const size_t OFF_DECX = OFF_ENCX + 4194304;     // 2,097,152
  const size_t OFF_WB   = OFF_DECX + 2097152;     // converted weights (bf16)
  const size_t WB_EIH = 0;                        // 4,194,304  (4096x512)
  const size_t WB_DIH = WB_EIH + 4194304;         // 2,097,152  (4096x256)
  const size_t WB_EHH = WB_DIH + 2097152;         // 8,388,608  (4096x1024)
  const size_t WB_DHH = WB_EHH + 8388608;         // 8,388,608
  const size_t WB_SCR = WB_DHH + 8388608;         // 10,240,000 (5000x1024)
  const size_t WB_END = WB_SCR + 10240000;        // 33,308,672 total
  const size_t OFF_EPRE = OFF_WB + WB_END;
  const size_t NEED_C = OFF_EPRE + 33554432;      // enc_pre
  const size_t NEED_B = NEED_C + 8388608;         // + dec_hs in ws
  const size_t NEED_A = NEED_B + 33554432;        // + dec_pre in ws

  ushort_t* hbuf  = (ushort_t*)(ws + OFF_HBUF);
  int*      flags = (int*)(ws + OFF_FLAG);
  int*      dflag = (int*)(ws + OFF_DIAG);
  ushort_t* enc_x = (ushort_t*)(ws + OFF_ENCX);
  ushort_t* dec_x = (ushort_t*)(ws + OFF_DECX);
  ushort_t* wb_eih = (ushort_t*)(ws + OFF_WB + WB_EIH);
  ushort_t* wb_dih = (ushort_t*)(ws + OFF_WB + WB_DIH);
  ushort_t* wb_ehh = (ushort_t*)(ws + OFF_WB + WB_EHH);
  ushort_t* wb_dhh = (ushort_t*)(ws + OFF_WB + WB_DHH);
  ushort_t* wb_scr = (ushort_t*)(ws + OFF_WB + WB_SCR);
  ushort_t* enc_pre = (ushort_t*)(ws + OFF_EPRE);

  hipMemsetAsync(ws, 0, OFF_ENCX, stream);   // hbuf=0 (h0,c0), flags=0, dflag=0
  probe_dtype<<<1, 256, 0, stream>>>((const ushort_t*)d_in[2], 262144, dflag);

  if (ws_size < NEED_C) {   // cannot run: report code 250 through absmax
    finalize_kernel<<<1, 64, 0, stream>>>(d_out, hbuf, dflag, 1);
    return;
  }

  ushort_t* dec_pre;
  ushort_t* dec_hs;
  if (ws_size >= NEED_A) {
    dec_pre = (ushort_t*)(ws + NEED_B);
    dec_hs  = (ushort_t*)(ws + NEED_C);
  } else if (ws_size >= NEED_B) {
    dec_pre = (ushort_t*)d_out;               // consumed before score GEMM writes out
    dec_hs  = (ushort_t*)(ws + NEED_C);
  } else {
    dec_pre = (ushort_t*)d_out;
    dec_hs  = enc_pre;                        // enc_pre only read t<128; dec_hs written t>=128
  }

  // convert weights to bf16 (or copy). Counts from in_sizes -- NEVER hand-computed.
  const int idxs[5] = {4, 8, 5, 9, 12};
  ushort_t* dsts[5] = {wb_eih, wb_dih, wb_ehh, wb_dhh, wb_scr};
  for (int k = 0; k < 5; ++k) {
    int n4 = in_sizes[idxs[k]] / 4;
    conv_w<<<(n4 + 255) / 256, 256, 0, stream>>>(d_in[idxs[k]], dsts[k], n4, dflag);
  }

  embed_kernel<<<3072, 256, 0, stream>>>(sentence, label_seq, d_in[2], d_in[3],
                                         enc_x, dec_x, dflag);

  gemm_bt_bias<<<dim3(32, 32), 256, 0, stream>>>(enc_x, wb_eih, enc_pre,
                                                 d_in[6], d_in[7], 4096, 4096, 512, dflag, 0);
  gemm_bt_bias<<<dim3(32, 32), 256, 0, stream>>>(dec_x, wb_dih, dec_pre,
                                                 d_in[10], d_in[11], 4096, 4096, 256, dflag, 0);

  sentinel_kernel<<<1, 64, 0, stream>>>(dec_hs);

  void* args[] = {(void*)&enc_pre, (void*)&dec_pre, (void*)&wb_ehh, (void*)&wb_dhh,
                  (void*)&hbuf, (void*)&dec_hs, (void*)&flags};
  hipLaunchCooperativeKernel((void*)recurrence_kernel, dim3(256), dim3(256),
                             args, 0, stream);

  gemm_bt_bias<<<dim3(40, 32), 256, 0, stream>>>(dec_hs, wb_scr, d_out,
                                                 d_in[13], nullptr, 4096, 5000, 1024, dflag, 1);

  // diagnostics: localize any NaN through the absmax channel
  scan_b16<<<2048, 256, 0, stream>>>(enc_pre, (size_t)4096 * 4096, dflag, 0);
  scan_b16<<<1024, 256, 0, stream>>>(dec_hs, (size_t)4096 * 1024, dflag, 1);
  scrub_out<<<2048, 256, 0, stream>>>(d_out, (size_t)4096 * 5000, dflag);
  finalize_kernel<<<1, 64, 0, stream>>>(d_out, dec_hs, dflag, 0);
}

// Round 6
// 2293.755 us; speedup vs baseline: 3.2134x; 3.2134x over previous
//
#include <hip/hip_runtime.h>
#include <hip/hip_bf16.h>
#include <cstdint>

using bf16 = __hip_bfloat16;
typedef unsigned short ushort_t;
typedef unsigned int uint_t;
typedef unsigned long long u64;
typedef __bf16 bf16x8 __attribute__((ext_vector_type(8)));
typedef float f32x4 __attribute__((ext_vector_type(4)));

#define MFMA16(a, b, c) __builtin_amdgcn_mfma_f32_16x16x32_bf16(a, b, c, 0, 0, 0)

// f32 -> bf16 bits, round-to-nearest-even
__device__ __forceinline__ ushort_t f2bu(float x) {
  uint_t b = __builtin_bit_cast(uint_t, x);
  b += 0x7FFFu + ((b >> 16) & 1u);
  return (ushort_t)(b >> 16);
}
__device__ __forceinline__ float bu2f(ushort_t u) {
  return __builtin_bit_cast(float, ((uint_t)u) << 16);
}
__device__ __forceinline__ int is_nan_bu(ushort_t u) { return (u & 0x7FFF) > 0x7F80; }

__device__ __forceinline__ float sigm(float x) { return 1.f / (1.f + __expf(-x)); }
__device__ __forceinline__ float tanh_fast(float x) {
  float e = __expf(2.f * x);
  return 1.f - 2.f / (e + 1.f);   // safe at +-inf
}

// coherent (agent-scope, cache-bypassing) 16B h load as two relaxed 8B atomics.
// Proven mechanism: round-5's flag polling used the same atomic path cross-XCD.
__device__ __forceinline__ bf16x8 load_h16(const ushort_t* p) {
  u64 lo = __hip_atomic_load((const u64*)p,       __ATOMIC_RELAXED, __HIP_MEMORY_SCOPE_AGENT);
  u64 hi = __hip_atomic_load((const u64*)(p + 4), __ATOMIC_RELAXED, __HIP_MEMORY_SCOPE_AGENT);
  union { u64 q[2]; bf16x8 v; } u;
  u.q[0] = lo; u.q[1] = hi;
  return u.v;
}

// ---------------------------------------------------------------------------
// dtype probe: f32 data read as ushorts shows ~0.4% bf16-NaN patterns; bf16
// data of 0.02 scale shows none. dflag[3]=1 -> inputs are f32.
// ---------------------------------------------------------------------------
__global__ void probe_dtype(const ushort_t* __restrict__ w, int n, int* __restrict__ dflag) {
  __shared__ int cnt;
  if (threadIdx.x == 0) cnt = 0;
  __syncthreads();
  int local = 0;
  for (int i = threadIdx.x; i < n; i += blockDim.x)
    if (is_nan_bu(w[i])) local++;
  if (local) atomicAdd(&cnt, local);
  __syncthreads();
  if (threadIdx.x == 0) dflag[3] = (cnt > 4) ? 1 : 0;
}

// ---------------------------------------------------------------------------
// weight convert (or copy): n4 from in_sizes/4 on host (never hand-computed).
// ---------------------------------------------------------------------------
__global__ void conv_w(const void* __restrict__ in, ushort_t* __restrict__ out,
                       int n4, const int* __restrict__ dflag) {
  int i = blockIdx.x * blockDim.x + threadIdx.x;
  if (i >= n4) return;
  uint2 o;
  if (dflag[3]) {
    float4 v = ((const float4*)in)[i];
    o.x = f2bu(v.x) | ((uint_t)f2bu(v.y) << 16);
    o.y = f2bu(v.z) | ((uint_t)f2bu(v.w) << 16);
  } else {
    o = ((const uint2*)in)[i];
  }
  ((uint2*)out)[i] = o;
}

// ---------------------------------------------------------------------------
// Embedding gather -> bf16 x-buffers.
// ---------------------------------------------------------------------------
__global__ void embed_kernel(const int* __restrict__ sentence, const int* __restrict__ label_seq,
                             const void* __restrict__ word_emb, const void* __restrict__ label_emb,
                             ushort_t* __restrict__ enc_x, ushort_t* __restrict__ dec_x,
                             const int* __restrict__ dflag) {
  const int mode = dflag[3];
  int c = blockIdx.x * blockDim.x + threadIdx.x;
  const int encC = 4096 * 128;
  const int decC = 4096 * 64;
  if (c < encC) {
    int r = c >> 7, off = c & 127;
    int tok = sentence[r];
    uint2 o;
    if (mode) {
      float4 v = ((const float4*)word_emb)[(size_t)tok * 128 + off];
      o.x = f2bu(v.x) | ((uint_t)f2bu(v.y) << 16);
      o.y = f2bu(v.z) | ((uint_t)f2bu(v.w) << 16);
    } else {
      o = ((const uint2*)word_emb)[(size_t)tok * 128 + off];
    }
    ((uint2*)enc_x)[(size_t)r * 128 + off] = o;
  } else if (c < encC + decC) {
    int cc = c - encC;
    int r = cc >> 6, off = cc & 63;
    int t = r >> 5, b = r & 31;
    int tok = (t == 0) ? 1 : label_seq[b * 128 + (t - 1)];
    uint2 o;
    if (mode) {
      float4 v = ((const float4*)label_emb)[(size_t)tok * 64 + off];
      o.x = f2bu(v.x) | ((uint_t)f2bu(v.y) << 16);
      o.y = f2bu(v.z) | ((uint_t)f2bu(v.w) << 16);
    } else {
      o = ((const uint2*)label_emb)[(size_t)tok * 64 + off];
    }
    ((uint2*)dec_x)[(size_t)r * 64 + off] = o;
  }
}

// ---------------------------------------------------------------------------
// C(M,N) = A(M,K) @ B(N,K)^T + bias1 + bias2. A,B bf16 bits, fp32 accum.
// store_mode: 0 = bf16 C[r*N+c]
//             1 = bf16 gate-interleaved (N==4096): C[r*4096 + (c&1023)*4 + (c>>10)]
//                 -> recurrence reads all 4 gates of a unit as one 8B load
//             2 = final output: f32 if dflag[3] else bf16
// ---------------------------------------------------------------------------
__global__ __launch_bounds__(256) void gemm_bt_bias(
    const ushort_t* __restrict__ A, const ushort_t* __restrict__ B, void* __restrict__ C,
    const void* __restrict__ bias1, const void* __restrict__ bias2,
    int M, int N, int K, const int* __restrict__ dflag, int store_mode) {
  __shared__ __align__(16) ushort_t sA[128 * 32];
  __shared__ __align__(16) ushort_t sB[128 * 32];
  const int tid = threadIdx.x;
  const int wave = tid >> 6, lane = tid & 63;
  const int quad = lane >> 4, col = lane & 15;
  const int bm = blockIdx.y * 128, bn = blockIdx.x * 128;
  const int wm = (wave >> 1) * 64, wn = (wave & 1) * 64;

  f32x4 acc[4][4] = {};

  const int c0i = tid, c1i = 256 + tid;
  const int r0 = c0i >> 2, kb0 = c0i & 3;
  const int r1 = c1i >> 2, kb1 = c1i & 3;
  const int j0 = (bn + r0 <= N - 1) ? (bn + r0) : (N - 1);
  const int j1 = (bn + r1 <= N - 1) ? (bn + r1) : (N - 1);

  for (int k0 = 0; k0 < K; k0 += 32) {
    uint4 va0 = *(const uint4*)(A + (size_t)(bm + r0) * K + (k0 + kb0 * 8));
    uint4 va1 = *(const uint4*)(A + (size_t)(bm + r1) * K + (k0 + kb1 * 8));
    uint4 vb0 = *(const uint4*)(B + (size_t)j0 * K + (k0 + kb0 * 8));
    uint4 vb1 = *(const uint4*)(B + (size_t)j1 * K + (k0 + kb1 * 8));
    __syncthreads();
    *(uint4*)((char*)sA + c0i * 16) = va0;
    *(uint4*)((char*)sA + c1i * 16) = va1;
    *(uint4*)((char*)sB + c0i * 16) = vb0;
    *(uint4*)((char*)sB + c1i * 16) = vb1;
    __syncthreads();

    bf16x8 af[4], bff[4];
#pragma unroll
    for (int mt = 0; mt < 4; ++mt)
      af[mt] = *(const bf16x8*)&sA[(wm + mt * 16 + col) * 32 + quad * 8];
#pragma unroll
    for (int nt = 0; nt < 4; ++nt)
      bff[nt] = *(const bf16x8*)&sB[(wn + nt * 16 + col) * 32 + quad * 8];
#pragma unroll
    for (int mt = 0; mt < 4; ++mt)
#pragma unroll
      for (int nt = 0; nt < 4; ++nt)
        acc[mt][nt] = MFMA16(af[mt], bff[nt], acc[mt][nt]);
  }

  const int mode = dflag[3];
  const int st_f32 = (store_mode == 2) && mode;
#pragma unroll
  for (int nt = 0; nt < 4; ++nt) {
    int c0 = bn + wn + nt * 16 + col;
    if (c0 >= N) continue;
    float bv = 0.f;
    if (bias1) bv += mode ? ((const float*)bias1)[c0] : bu2f(((const ushort_t*)bias1)[c0]);
    if (bias2) bv += mode ? ((const float*)bias2)[c0] : bu2f(((const ushort_t*)bias2)[c0]);
#pragma unroll
    for (int mt = 0; mt < 4; ++mt) {
      int r0e = bm + wm + mt * 16 + quad * 4;
#pragma unroll
      for (int r = 0; r < 4; ++r) {
        float v = acc[mt][nt][r] + bv;
        size_t idx;
        if (store_mode == 1) idx = (size_t)(r0e + r) * 4096 + (size_t)(c0 & 1023) * 4 + (c0 >> 10);
        else                 idx = (size_t)(r0e + r) * N + c0;
        if (st_f32) ((float*)C)[idx] = v;
        else        ((ushort_t*)C)[idx] = f2bu(v);
      }
    }
  }
}

// ---------------------------------------------------------------------------
// Persistent LSTM recurrence, 256 WGs x 256 thr, cooperative, 256 steps.
// Round-6 changes vs round 5 (which ran 25us/step, VALUBusy 0.6%):
//  - NO __threadfence / NO release stores (those lowered to full-L2 wb/inv per
//    wave per step -> L2 never retained the read-only pre-gates -> 345MB HBM
//    refetch + latency stall). Shared data (h, flags, epoch) instead uses
//    relaxed agent-scope atomics (cache-bypassing; mechanism HW-proven by
//    round-5's working flag barrier). Read-only pre/W stay L2-cached.
//  - Two-level barrier: per-WG flag on its own 64B line; WG0 polls all 256,
//    publishes epoch; everyone else polls the single epoch line (1 coalesced
//    load/wave) -- ~130x less coherence-point traffic.
//  - u0 XCD-swizzled: same-XCD WGs (wg%8, MI300-style round robin) cover a
//    contiguous 128-unit block -> each pre-gate line fetched by 1 XCD, not 8.
//  - pre-gates gate-interleaved (store_mode 1): one 8B read/thread/step.
// ---------------------------------------------------------------------------
#define REC_SLAB  33024                  // 16 rows * 1032 halfs * 2B
#define PART_BYTES 8704                  // 4 waves * 32*17 f32
#define REC_SMEM  (REC_SLAB + PART_BYTES + 256)
#define FLAG_STRIDE 16                   // ints: one 64B line per WG

__device__ __forceinline__ void load_slab(const ushort_t* __restrict__ W, char* slab,
                                          int u0, int tid) {
  for (int i = 0; i < 8; ++i) {
    int c = i * 256 + tid;               // 0..2047 16B chunks
    int s = c >> 7, off = c & 127;
    int j = (s >> 2) * 1024 + u0 + (s & 3);
    *(uint4*)(slab + s * 2064 + off * 16) =
        *(const uint4*)(W + (size_t)j * 1024 + off * 8);
  }
}

__global__ __launch_bounds__(256, 1) void recurrence_kernel(
    const ushort_t* __restrict__ enc_pre, const ushort_t* __restrict__ dec_pre,
    const ushort_t* __restrict__ encW, const ushort_t* __restrict__ decW,
    ushort_t* __restrict__ hbuf, ushort_t* __restrict__ dec_hs,
    int* __restrict__ flags, int* __restrict__ epoch) {
  __shared__ __align__(16) char smem[REC_SMEM];
  const int tid = threadIdx.x;
  const int wg = blockIdx.x;             // 0..255
  const int wave = tid >> 6, lane = tid & 63;
  const int quad = lane >> 4, col = lane & 15;
  // XCD-contiguous unit block: WGs with equal wg%8 cover 128 consecutive units
  const int u0 = (((wg & 7) << 5) | (wg >> 3)) << 2;

  load_slab(encW, smem, u0, tid);
  float* part = (float*)(smem + REC_SLAB);
  ushort_t* hlds = (ushort_t*)(smem + REC_SLAB + PART_BYTES);
  const int cb = tid >> 2;               // tid<128: batch 0..31
  const int cu = tid & 3;                // unit 0..3
  float c_state = 0.f;
  __syncthreads();

  for (int t = 0; t < 256; ++t) {
    const bool dec = (t >= 128);
    if (t == 128) {
      load_slab(decW, smem, u0, tid);
      __syncthreads();
    }
    const int tt = dec ? (t - 128) : t;
    const ushort_t* pre = dec ? dec_pre : enc_pre;

    // x-pre-gates: gate-interleaved layout -> one 8B cached load (L2-stable now)
    float g0 = 0.f, g1 = 0.f, g2 = 0.f, g3 = 0.f;
    if (tid < 128) {
      uint2 pg = *(const uint2*)(pre + ((size_t)(tt * 32 + cb)) * 4096 + (size_t)(u0 + cu) * 4);
      g0 = bu2f((ushort_t)(pg.x & 0xffff));
      g1 = bu2f((ushort_t)(pg.x >> 16));
      g2 = bu2f((ushort_t)(pg.y & 0xffff));
      g3 = bu2f((ushort_t)(pg.y >> 16));
    }

    // gates partial: wave covers K in [wave*256, wave*256+256); h via coherent loads
    const ushort_t* hr = hbuf + (size_t)(t & 1) * (32 * 1024);
    const int kbase = wave * 256 + quad * 8;
    const ushort_t* a_base0 = hr + (size_t)col * 1024 + kbase;
    const ushort_t* a_base1 = hr + (size_t)(16 + col) * 1024 + kbase;
    const char* b_base = smem + col * 2064 + kbase * 2;
    f32x4 acc0 = {}, acc1 = {};
#pragma unroll
    for (int kt = 0; kt < 8; ++kt) {
      bf16x8 a0 = load_h16(a_base0 + kt * 32);
      bf16x8 a1 = load_h16(a_base1 + kt * 32);
      bf16x8 b0 = *(const bf16x8*)(b_base + kt * 64);
      acc0 = MFMA16(a0, b0, acc0);
      acc1 = MFMA16(a1, b0, acc1);
    }
    float* pw = part + wave * (32 * 17);
#pragma unroll
    for (int r = 0; r < 4; ++r) {
      pw[(quad * 4 + r) * 17 + col]      = acc0[r];
      pw[(16 + quad * 4 + r) * 17 + col] = acc1[r];
    }
    __syncthreads();

    if (tid < 128) {
#pragma unroll
      for (int w = 0; w < 4; ++w) {
        const float* pr = part + w * (32 * 17) + cb * 17;
        g0 += pr[cu];
        g1 += pr[4 + cu];
        g2 += pr[8 + cu];
        g3 += pr[12 + cu];
      }
      float ig = sigm(g0), fg = sigm(g1), gg = tanh_fast(g2), og = sigm(g3);
      c_state = fg * c_state + ig * gg;
      float hv = og * tanh_fast(c_state);
      ushort_t hb = f2bu(hv);
      hlds[tid] = hb;                                        // tid = cb*4+cu
      if (dec) dec_hs[((size_t)tt * 32 + cb) * 1024 + u0 + cu] = hb;  // plain store
    }
    __syncthreads();

    // publish h: 32 coherent 8B stores per WG (4 units packed per batch row)
    ushort_t* hw = hbuf + (size_t)((t + 1) & 1) * (32 * 1024);
    if (tid < 32) {
      uint2 two = ((const uint2*)hlds)[tid];
      u64 v = ((u64)two.y << 32) | two.x;
      __hip_atomic_store((u64*)(hw + (size_t)tid * 1024 + u0), v,
                         __ATOMIC_RELAXED, __HIP_MEMORY_SCOPE_AGENT);
    }
    __syncthreads();                     // drains each thread's stores (vmcnt0)

    if (tid == 0)
      __hip_atomic_store(&flags[wg * FLAG_STRIDE], t + 1,
                         __ATOMIC_RELAXED, __HIP_MEMORY_SCOPE_AGENT);
    const int target = t + 1;
    if (wg == 0) {
      if (wave == 0) {
        for (;;) {
          int f0 = __hip_atomic_load(&flags[(lane)       * FLAG_STRIDE], __ATOMIC_RELAXED, __HIP_MEMORY_SCOPE_AGENT);
          int f1 = __hip_atomic_load(&flags[(64  + lane) * FLAG_STRIDE], __ATOMIC_RELAXED, __HIP_MEMORY_SCOPE_AGENT);
          int f2 = __hip_atomic_load(&flags[(128 + lane) * FLAG_STRIDE], __ATOMIC_RELAXED, __HIP_MEMORY_SCOPE_AGENT);
          int f3 = __hip_atomic_load(&flags[(192 + lane) * FLAG_STRIDE], __ATOMIC_RELAXED, __HIP_MEMORY_SCOPE_AGENT);
          if (__all((f0 >= target) & (f1 >= target) & (f2 >= target) & (f3 >= target))) break;
        }
        if (lane == 0)
          __hip_atomic_store(epoch, target, __ATOMIC_RELAXED, __HIP_MEMORY_SCOPE_AGENT);
      }
    } else if (wave == 0) {
      // single line, same address all lanes -> one coalesced request per poll
      while (__hip_atomic_load(epoch, __ATOMIC_RELAXED, __HIP_MEMORY_SCOPE_AGENT) < target) {}
    }
    __syncthreads();
  }
}

// ---------------------------------------------------------------------------
extern "C" void kernel_launch(void* const* d_in, const int* in_sizes, int n_in,
                              void* d_out, int out_size, void* d_ws, size_t ws_size,
                              hipStream_t stream) {
  const int* sentence  = (const int*)d_in[0];
  const int* label_seq = (const int*)d_in[1];

  char* ws = (char*)d_ws;
  // ws layout (bytes)
  const size_t OFF_HBUF  = 0;                         // 131072 (2 x 32x1024 bf16)
  const size_t OFF_FLAG  = 131072;                    // 256 * 64B = 16384
  const size_t OFF_EPOCH = OFF_FLAG + 16384;          // 64
  const size_t OFF_DIAG  = OFF_EPOCH + 64;            // 16
  const size_t OFF_ENCX  = 147968;                    // aligned
  const size_t OFF_DECX  = OFF_ENCX + 4194304;
  const size_t OFF_WB    = OFF_DECX + 2097152;
  const size_t WB_EIH = 0;                            // 4,194,304  (4096x512)
  const size_t WB_DIH = WB_EIH + 4194304;             // 2,097,152  (4096x256)
  const size_t WB_EHH = WB_DIH + 2097152;             // 8,388,608  (4096x1024)
  const size_t WB_DHH = WB_EHH + 8388608;             // 8,388,608
  const size_t WB_SCR = WB_DHH + 8388608;             // 10,240,000 (5000x1024)
  const size_t WB_END = WB_SCR + 10240000;
  const size_t OFF_EPRE = OFF_WB + WB_END;
  const size_t NEED_C = OFF_EPRE + 33554432;          // enc_pre
  const size_t NEED_B = NEED_C + 8388608;             // + dec_hs in ws
  const size_t NEED_A = NEED_B + 33554432;            // + dec_pre in ws

  ushort_t* hbuf   = (ushort_t*)(ws + OFF_HBUF);
  int*      flags  = (int*)(ws + OFF_FLAG);
  int*      epoch  = (int*)(ws + OFF_EPOCH);
  int*      dflag  = (int*)(ws + OFF_DIAG);
  ushort_t* enc_x  = (ushort_t*)(ws + OFF_ENCX);
  ushort_t* dec_x  = (ushort_t*)(ws + OFF_DECX);
  ushort_t* wb_eih = (ushort_t*)(ws + OFF_WB + WB_EIH);
  ushort_t* wb_dih = (ushort_t*)(ws + OFF_WB + WB_DIH);
  ushort_t* wb_ehh = (ushort_t*)(ws + OFF_WB + WB_EHH);
  ushort_t* wb_dhh = (ushort_t*)(ws + OFF_WB + WB_DHH);
  ushort_t* wb_scr = (ushort_t*)(ws + OFF_WB + WB_SCR);
  ushort_t* enc_pre = (ushort_t*)(ws + OFF_EPRE);

  hipMemsetAsync(ws, 0, OFF_ENCX, stream);   // h0/c0, flags, epoch, dflag = 0
  probe_dtype<<<1, 256, 0, stream>>>((const ushort_t*)d_in[2], 262144, dflag);

  if (ws_size < NEED_C) return;   // cannot run

  ushort_t* dec_pre;
  ushort_t* dec_hs;
  if (ws_size >= NEED_A) {
    dec_pre = (ushort_t*)(ws + NEED_B);
    dec_hs  = (ushort_t*)(ws + NEED_C);
  } else if (ws_size >= NEED_B) {
    dec_pre = (ushort_t*)d_out;               // consumed before score GEMM writes out
    dec_hs  = (ushort_t*)(ws + NEED_C);
  } else {
    dec_pre = (ushort_t*)d_out;
    dec_hs  = enc_pre;                        // enc_pre read only t<128; dec_hs written t>=128
  }

  // weights -> bf16 (counts strictly from in_sizes)
  const int idxs[5] = {4, 8, 5, 9, 12};
  ushort_t* dsts[5] = {wb_eih, wb_dih, wb_ehh, wb_dhh, wb_scr};
  for (int k = 0; k < 5; ++k) {
    int n4 = in_sizes[idxs[k]] / 4;
    conv_w<<<(n4 + 255) / 256, 256, 0, stream>>>(d_in[idxs[k]], dsts[k], n4, dflag);
  }

  embed_kernel<<<3072, 256, 0, stream>>>(sentence, label_seq, d_in[2], d_in[3],
                                         enc_x, dec_x, dflag);

  // pre-gates, gate-interleaved (store_mode 1)
  gemm_bt_bias<<<dim3(32, 32), 256, 0, stream>>>(enc_x, wb_eih, enc_pre,
                                                 d_in[6], d_in[7], 4096, 4096, 512, dflag, 1);
  gemm_bt_bias<<<dim3(32, 32), 256, 0, stream>>>(dec_x, wb_dih, dec_pre,
                                                 d_in[10], d_in[11], 4096, 4096, 256, dflag, 1);

  void* args[] = {(void*)&enc_pre, (void*)&dec_pre, (void*)&wb_ehh, (void*)&wb_dhh,
                  (void*)&hbuf, (void*)&dec_hs, (void*)&flags, (void*)&epoch};
  hipLaunchCooperativeKernel((void*)recurrence_kernel, dim3(256), dim3(256),
                             args, 0, stream);

  // score: dec_hs(4096,1024) @ W_score(5000,1024)^T + b_score -> out
  gemm_bt_bias<<<dim3(40, 32), 256, 0, stream>>>(dec_hs, wb_scr, d_out,
                                                 d_in[13], nullptr, 4096, 5000, 1024, dflag, 2);
}